// Round 1
// baseline (697.304 us; speedup 1.0000x reference)
//
#include <hip/hip_runtime.h>
#include <hip/hip_bf16.h>

// Problem constants
#define NSEQ   128        // BS*C
#define SEQLEN 64         // D
#define HWHW   9216       // 96*96
#define CHELEM 589824     // D*HW*HW floats per (b,c) channel

__device__ __forceinline__ float sigm(float x) {
    return 1.0f / (1.0f + __expf(-x));
}
__device__ __forceinline__ float tanhfast(float x) {
    x = fmaxf(x, -44.0f);                 // avoid exp overflow -> NaN
    float e = __expf(-2.0f * x);
    return (1.0f - e) / (1.0f + e);
}

// ---------------------------------------------------------------------------
// Kernel 1: mean over H,W for each (b,c,d).  One block per (b,c,d).
// ---------------------------------------------------------------------------
__global__ __launch_bounds__(256) void mean_kernel(const float* __restrict__ x,
                                                   float* __restrict__ means) {
    const int bidx = blockIdx.x;                       // 0..8191
    const float4* xp = (const float4*)(x + (size_t)bidx * HWHW);
    const int tid = threadIdx.x;
    float sum = 0.f;
#pragma unroll
    for (int i = 0; i < 9; ++i) {                      // 9*256*4 = 9216
        float4 v = xp[tid + i * 256];
        sum += v.x + v.y + v.z + v.w;
    }
#pragma unroll
    for (int off = 32; off; off >>= 1) sum += __shfl_down(sum, off, 64);
    __shared__ float wsum[4];
    const int wave = tid >> 6, lane = tid & 63;
    if (lane == 0) wsum[wave] = sum;
    __syncthreads();
    if (tid == 0)
        means[bidx] = (wsum[0] + wsum[1] + wsum[2] + wsum[3]) * (1.0f / 9216.0f);
}

// ---------------------------------------------------------------------------
// Kernel 2: BiLSTM (2 layers) + SE FC stack.  ONE block, 256 threads.
// Thread pair (2s, 2s+1) owns sequence s.
//   Layer 0: tid&1 == 0 -> forward dir, ==1 -> backward dir (full gates).
//   Layer 1: tid&1 splits the 16 gates (i,f | g,o), h/c exchanged via shfl.
// ---------------------------------------------------------------------------
__global__ __launch_bounds__(256) void lstm_fc_kernel(
    const float* __restrict__ means,
    const float* __restrict__ wih0f, const float* __restrict__ whh0f,
    const float* __restrict__ bih0f, const float* __restrict__ bhh0f,
    const float* __restrict__ wih0b, const float* __restrict__ whh0b,
    const float* __restrict__ bih0b, const float* __restrict__ bhh0b,
    const float* __restrict__ wih1f, const float* __restrict__ whh1f,
    const float* __restrict__ bih1f, const float* __restrict__ bhh1f,
    const float* __restrict__ wih1b, const float* __restrict__ whh1b,
    const float* __restrict__ bih1b, const float* __restrict__ bhh1b,
    const float* __restrict__ w1,    const float* __restrict__ w2,
    float* __restrict__ l0out,        // [128][64][8] scratch
    float* __restrict__ scl)          // [128] output scales
{
    const int tid  = threadIdx.x;
    const int s    = tid >> 1;        // sequence 0..127
    const int half = tid & 1;

    __shared__ float lastout[NSEQ][8];   // last-timestep layer1 output
    __shared__ float hidden[64];         // FC1 output [2][32]

    // ---------------- layer 0 (one thread per seq+direction) ----------------
    {
        const float* wih = half ? wih0b : wih0f;
        const float* whh = half ? whh0b : whh0f;
        const float* bi  = half ? bih0b : bih0f;
        const float* bh  = half ? bhh0b : bhh0f;
        float Wx[16], B[16], Wh[16][4];
#pragma unroll
        for (int g = 0; g < 16; ++g) {
            Wx[g] = wih[g];
            B[g]  = bi[g] + bh[g];
#pragma unroll
            for (int j = 0; j < 4; ++j) Wh[g][j] = whh[g * 4 + j];
        }
        float h[4] = {0, 0, 0, 0}, c[4] = {0, 0, 0, 0};
        const float* seq = means + s * SEQLEN;
        float xnext = seq[half ? (SEQLEN - 1) : 0];
        for (int t = 0; t < SEQLEN; ++t) {
            const int tt = half ? (SEQLEN - 1 - t) : t;
            const float xt = xnext;
            if (t < SEQLEN - 1) xnext = seq[half ? (SEQLEN - 2 - t) : (t + 1)];
            float g[16];
#pragma unroll
            for (int gi = 0; gi < 16; ++gi)
                g[gi] = fmaf(Wx[gi], xt, B[gi]) + Wh[gi][0] * h[0] + Wh[gi][1] * h[1]
                      + Wh[gi][2] * h[2] + Wh[gi][3] * h[3];
#pragma unroll
            for (int j = 0; j < 4; ++j) {
                c[j] = sigm(g[4 + j]) * c[j] + sigm(g[j]) * tanhfast(g[8 + j]);
                h[j] = sigm(g[12 + j]) * tanhfast(c[j]);
            }
            *(float4*)(l0out + (s * SEQLEN + tt) * 8 + half * 4) =
                make_float4(h[0], h[1], h[2], h[3]);
        }
    }
    __threadfence_block();
    __syncthreads();

    // ---------------- layer 1 forward (gate-split across lane pair) ---------
    {
        const float* wihr = wih1f + half * 8 * 8;
        const float* whhr = whh1f + half * 8 * 4;
        const float* bir  = bih1f + half * 8;
        const float* bhr  = bhh1f + half * 8;
        float Wx[8][8], Wh[8][4], B[8];
#pragma unroll
        for (int g = 0; g < 8; ++g) {
            B[g] = bir[g] + bhr[g];
#pragma unroll
            for (int k = 0; k < 8; ++k) Wx[g][k] = wihr[g * 8 + k];
#pragma unroll
            for (int j = 0; j < 4; ++j) Wh[g][j] = whhr[g * 4 + j];
        }
        float h[4] = {0, 0, 0, 0}, c[4] = {0, 0, 0, 0};
        const float* base = l0out + s * SEQLEN * 8;
        float4 inA = *(const float4*)(base);
        float4 inB = *(const float4*)(base + 4);
        for (int t = 0; t < SEQLEN; ++t) {
            const float in[8] = {inA.x, inA.y, inA.z, inA.w, inB.x, inB.y, inB.z, inB.w};
            if (t < SEQLEN - 1) {
                inA = *(const float4*)(base + (t + 1) * 8);
                inB = *(const float4*)(base + (t + 1) * 8 + 4);
            }
            float g[8];
#pragma unroll
            for (int gi = 0; gi < 8; ++gi) {
                float acc = B[gi];
#pragma unroll
                for (int k = 0; k < 8; ++k) acc = fmaf(Wx[gi][k], in[k], acc);
#pragma unroll
                for (int j = 0; j < 4; ++j) acc = fmaf(Wh[gi][j], h[j], acc);
                g[gi] = acc;
            }
            // half0: g[0..3]=i gates, g[4..7]=f gates
            // half1: g[0..3]=g gates, g[4..7]=o gates
            float a[4], bg[4];
#pragma unroll
            for (int j = 0; j < 4; ++j) {
                a[j]  = half ? tanhfast(g[j]) : sigm(g[j]);
                bg[j] = sigm(g[4 + j]);
            }
#pragma unroll
            for (int j = 0; j < 4; ++j) {
                const float tg = __shfl_xor(a[j], 1);        // half0 gets tanh(gg)
                c[j] = bg[j] * c[j] + a[j] * tg;             // valid on half0
                const float tc  = tanhfast(c[j]);
                const float tcx = __shfl_xor(tc, 1);         // half1 gets tanh(c)
                const float hnew = bg[j] * tcx;              // valid on half1
                const float hx   = __shfl_xor(hnew, 1);      // half0 gets h
                h[j] = half ? hnew : hx;                     // both now hold h
            }
        }
        if (!half) {
            lastout[s][0] = h[0]; lastout[s][1] = h[1];
            lastout[s][2] = h[2]; lastout[s][3] = h[3];
        }
    }

    // ---------------- layer 1 backward: only ONE step needed ----------------
    // (output taken at last original position == first step of reversed seq)
    {
        const float* wihr = wih1b + half * 8 * 8;
        const float* bir  = bih1b + half * 8;
        const float* bhr  = bhh1b + half * 8;
        const float* base = l0out + (s * SEQLEN + SEQLEN - 1) * 8;
        float4 inA = *(const float4*)(base);
        float4 inB = *(const float4*)(base + 4);
        const float in[8] = {inA.x, inA.y, inA.z, inA.w, inB.x, inB.y, inB.z, inB.w};
        float g[8];
#pragma unroll
        for (int gi = 0; gi < 8; ++gi) {
            float acc = bir[gi] + bhr[gi];
#pragma unroll
            for (int k = 0; k < 8; ++k) acc = fmaf(wihr[gi * 8 + k], in[k], acc);
            g[gi] = acc;
        }
        float a[4], bg[4];
#pragma unroll
        for (int j = 0; j < 4; ++j) {
            a[j]  = half ? tanhfast(g[j]) : sigm(g[j]);
            bg[j] = sigm(g[4 + j]);
        }
#pragma unroll
        for (int j = 0; j < 4; ++j) {
            const float tg   = __shfl_xor(a[j], 1);
            const float cnew = a[j] * tg;                    // c0 = 0
            const float tc   = tanhfast(cnew);
            const float tcx  = __shfl_xor(tc, 1);
            const float hnew = bg[j] * tcx;                  // valid on half1
            if (half) lastout[s][4 + j] = hnew;
        }
    }
    __syncthreads();

    // ---------------- FC1: hidden[b][m] = relu(feat[b] . w1[m]) -------------
    // feat[b][k] = lastout-flat[b*512 + k]   (k = c*8 + j)
    {
        const float* lastflat = &lastout[0][0];
        const int wave = tid >> 6, lane = tid & 63;
#pragma unroll
        for (int r = 0; r < 16; ++r) {
            const int o = wave * 16 + r;           // 0..63
            const int b = o >> 5, m = o & 31;
            float p = 0.f;
#pragma unroll
            for (int i = 0; i < 8; ++i) {
                const int k = lane + i * 64;
                p = fmaf(lastflat[b * 512 + k], w1[m * 512 + k], p);
            }
#pragma unroll
            for (int off = 32; off; off >>= 1) p += __shfl_down(p, off, 64);
            if (lane == 0) hidden[b * 32 + m] = fmaxf(p, 0.f);
        }
    }
    __syncthreads();

    // ---------------- FC2 + sigmoid -> per-channel scale ---------------------
    if (tid < 128) {
        const int b = tid >> 6, cc = tid & 63;
        float p = 0.f;
#pragma unroll
        for (int m = 0; m < 32; ++m)
            p = fmaf(hidden[b * 32 + m], w2[cc * 32 + m], p);
        scl[tid] = sigm(p);                       // tid == b*64 + cc
    }
}

// ---------------------------------------------------------------------------
// Kernel 3: out = x * scale[channel].  grid = (144 chunks, 128 channels).
// ---------------------------------------------------------------------------
__global__ __launch_bounds__(256) void scale_kernel(const float* __restrict__ x,
                                                    const float* __restrict__ scl,
                                                    float* __restrict__ out) {
    const int ch = blockIdx.y;                    // 0..127  (= b*64 + c)
    const float sv = scl[ch];
    const size_t base = (size_t)ch * CHELEM + (size_t)blockIdx.x * 4096;
    const float4* xp = (const float4*)(x + base);
    float4* op = (float4*)(out + base);
    const int tid = threadIdx.x;
#pragma unroll
    for (int i = 0; i < 4; ++i) {
        float4 v = xp[tid + i * 256];
        v.x *= sv; v.y *= sv; v.z *= sv; v.w *= sv;
        op[tid + i * 256] = v;
    }
}

// ---------------------------------------------------------------------------
extern "C" void kernel_launch(void* const* d_in, const int* in_sizes, int n_in,
                              void* d_out, int out_size, void* d_ws, size_t ws_size,
                              hipStream_t stream) {
    const float* x     = (const float*)d_in[0];
    const float* wih0f = (const float*)d_in[1];
    const float* whh0f = (const float*)d_in[2];
    const float* bih0f = (const float*)d_in[3];
    const float* bhh0f = (const float*)d_in[4];
    const float* wih0b = (const float*)d_in[5];
    const float* whh0b = (const float*)d_in[6];
    const float* bih0b = (const float*)d_in[7];
    const float* bhh0b = (const float*)d_in[8];
    const float* wih1f = (const float*)d_in[9];
    const float* whh1f = (const float*)d_in[10];
    const float* bih1f = (const float*)d_in[11];
    const float* bhh1f = (const float*)d_in[12];
    const float* wih1b = (const float*)d_in[13];
    const float* whh1b = (const float*)d_in[14];
    const float* bih1b = (const float*)d_in[15];
    const float* bhh1b = (const float*)d_in[16];
    const float* w1    = (const float*)d_in[17];
    const float* w2    = (const float*)d_in[18];
    float* out = (float*)d_out;

    float* ws    = (float*)d_ws;
    float* means = ws;                        // 8192 floats
    float* l0out = ws + 8192;                 // 128*64*8 = 65536 floats
    float* scl   = ws + 8192 + 65536;         // 128 floats

    mean_kernel<<<dim3(8192), dim3(256), 0, stream>>>(x, means);
    lstm_fc_kernel<<<dim3(1), dim3(256), 0, stream>>>(
        means,
        wih0f, whh0f, bih0f, bhh0f, wih0b, whh0b, bih0b, bhh0b,
        wih1f, whh1f, bih1f, bhh1f, wih1b, whh1b, bih1b, bhh1b,
        w1, w2, l0out, scl);
    scale_kernel<<<dim3(144, 128), dim3(256), 0, stream>>>(x, scl, out);
}

// Round 5
// 684.271 us; speedup vs baseline: 1.0190x; 1.0190x over previous
//
#include <hip/hip_runtime.h>
#include <hip/hip_bf16.h>

// Problem constants
#define NSEQ   128        // BS*C
#define SEQLEN 64         // D
#define HWHW   9216       // 96*96
#define CHELEM 589824     // D*HW*HW floats per (b,c) channel
#define NCHUNK 144        // CHELEM / 4096

typedef float v4f __attribute__((ext_vector_type(4)));

__device__ __forceinline__ float sigm(float x) {
    return 1.0f / (1.0f + __expf(-x));
}
__device__ __forceinline__ float tanhfast(float x) {
    x = fmaxf(x, -44.0f);                 // avoid exp overflow -> NaN
    float e = __expf(-2.0f * x);
    return (1.0f - e) / (1.0f + e);
}

// ---------------------------------------------------------------------------
// Kernel 1: mean over H,W for each (b,c,d).  One block per (b,c,d).
// Plain (cached) loads on purpose: we WANT x resident in the 256MB LLC so the
// reverse-order scale pass can hit it.
// ---------------------------------------------------------------------------
__global__ __launch_bounds__(256) void mean_kernel(const float* __restrict__ x,
                                                   float* __restrict__ means) {
    const int bidx = blockIdx.x;                       // 0..8191
    const v4f* xp = (const v4f*)(x + (size_t)bidx * HWHW);
    const int tid = threadIdx.x;
    float sum = 0.f;
#pragma unroll
    for (int i = 0; i < 9; ++i) {                      // 9*256*4 = 9216
        v4f v = xp[tid + i * 256];
        sum += v[0] + v[1] + v[2] + v[3];
    }
#pragma unroll
    for (int off = 32; off; off >>= 1) sum += __shfl_down(sum, off, 64);
    __shared__ float wsum[4];
    const int wave = tid >> 6, lane = tid & 63;
    if (lane == 0) wsum[wave] = sum;
    __syncthreads();
    if (tid == 0)
        means[bidx] = (wsum[0] + wsum[1] + wsum[2] + wsum[3]) * (1.0f / 9216.0f);
}

// ---------------------------------------------------------------------------
// Kernel 2: BiLSTM (2 layers) + SE FC stack.  ONE block, 256 threads.
// Thread pair (2s, 2s+1) owns sequence s.
//   Layer 0: tid&1 == 0 -> forward dir, ==1 -> backward dir (full gates).
//   Layer 1: tid&1 splits 16 gates (i,f | g,o); both halves keep redundant
//   copies of c,h so only TWO parallel shfls per gate-group are needed.
// ---------------------------------------------------------------------------
__global__ __launch_bounds__(256) void lstm_fc_kernel(
    const float* __restrict__ means,
    const float* __restrict__ wih0f, const float* __restrict__ whh0f,
    const float* __restrict__ bih0f, const float* __restrict__ bhh0f,
    const float* __restrict__ wih0b, const float* __restrict__ whh0b,
    const float* __restrict__ bih0b, const float* __restrict__ bhh0b,
    const float* __restrict__ wih1f, const float* __restrict__ whh1f,
    const float* __restrict__ bih1f, const float* __restrict__ bhh1f,
    const float* __restrict__ wih1b, const float* __restrict__ whh1b,
    const float* __restrict__ bih1b, const float* __restrict__ bhh1b,
    const float* __restrict__ w1,    const float* __restrict__ w2,
    float* __restrict__ l0out,        // [128][64][8] scratch (L2-resident)
    float* __restrict__ scl)          // [128] output scales
{
    const int tid  = threadIdx.x;
    const int s    = tid >> 1;        // sequence 0..127
    const int half = tid & 1;

    __shared__ float lastout[NSEQ][8];   // last-timestep layer1 output
    __shared__ float hidden[64];         // FC1 output [2][32]

    // ---------------- layer 0 (one thread per seq+direction) ----------------
    {
        const float* wih = half ? wih0b : wih0f;
        const float* whh = half ? whh0b : whh0f;
        const float* bi  = half ? bih0b : bih0f;
        const float* bh  = half ? bhh0b : bhh0f;
        float Wx[16], B[16], Wh[16][4];
#pragma unroll
        for (int g = 0; g < 16; ++g) {
            Wx[g] = wih[g];
            B[g]  = bi[g] + bh[g];
#pragma unroll
            for (int j = 0; j < 4; ++j) Wh[g][j] = whh[g * 4 + j];
        }
        float h[4] = {0, 0, 0, 0}, c[4] = {0, 0, 0, 0};
        const float* seq = means + s * SEQLEN;
        float xnext = seq[half ? (SEQLEN - 1) : 0];
        for (int t = 0; t < SEQLEN; ++t) {
            const int tt = half ? (SEQLEN - 1 - t) : t;
            const float xt = xnext;
            if (t < SEQLEN - 1) xnext = seq[half ? (SEQLEN - 2 - t) : (t + 1)];
            float g[16];
#pragma unroll
            for (int gi = 0; gi < 16; ++gi)
                g[gi] = fmaf(Wx[gi], xt, B[gi]) + Wh[gi][0] * h[0] + Wh[gi][1] * h[1]
                      + Wh[gi][2] * h[2] + Wh[gi][3] * h[3];
#pragma unroll
            for (int j = 0; j < 4; ++j) {
                c[j] = sigm(g[4 + j]) * c[j] + sigm(g[j]) * tanhfast(g[8 + j]);
                h[j] = sigm(g[12 + j]) * tanhfast(c[j]);
            }
            *(float4*)(l0out + (s * SEQLEN + tt) * 8 + half * 4) =
                make_float4(h[0], h[1], h[2], h[3]);
        }
    }
    __threadfence_block();
    __syncthreads();

    // ---------------- layer 1 forward (gate-split across lane pair) ---------
    // half0 gates: i (g[0..3]), f (g[4..7]);  half1 gates: g (g[0..3]), o (g[4..7])
    {
        const float* wihr = wih1f + half * 8 * 8;
        const float* whhr = whh1f + half * 8 * 4;
        const float* bir  = bih1f + half * 8;
        const float* bhr  = bhh1f + half * 8;
        float Wx[8][8], Wh[8][4], B[8];
#pragma unroll
        for (int g = 0; g < 8; ++g) {
            B[g] = bir[g] + bhr[g];
#pragma unroll
            for (int k = 0; k < 8; ++k) Wx[g][k] = wihr[g * 8 + k];
#pragma unroll
            for (int j = 0; j < 4; ++j) Wh[g][j] = whhr[g * 4 + j];
        }
        float h[4] = {0, 0, 0, 0}, c[4] = {0, 0, 0, 0};
        const float* base = l0out + s * SEQLEN * 8;
        float4 inA = *(const float4*)(base);
        float4 inB = *(const float4*)(base + 4);
        for (int t = 0; t < SEQLEN; ++t) {
            const float in[8] = {inA.x, inA.y, inA.z, inA.w, inB.x, inB.y, inB.z, inB.w};
            if (t < SEQLEN - 1) {
                inA = *(const float4*)(base + (t + 1) * 8);
                inB = *(const float4*)(base + (t + 1) * 8 + 4);
            }
            float g[8];
#pragma unroll
            for (int gi = 0; gi < 8; ++gi) {
                float acc = B[gi];
#pragma unroll
                for (int k = 0; k < 8; ++k) acc = fmaf(Wx[gi][k], in[k], acc);
#pragma unroll
                for (int j = 0; j < 4; ++j) acc = fmaf(Wh[gi][j], h[j], acc);
                g[gi] = acc;
            }
            float a[4], bg[4];
#pragma unroll
            for (int j = 0; j < 4; ++j) {
                a[j]  = half ? tanhfast(g[j]) : sigm(g[j]);   // sigm(i) | tanh(g)
                bg[j] = sigm(g[4 + j]);                       // sigm(f) | sigm(o)
            }
            // two PARALLEL exchanges; both halves then update identical c,h
#pragma unroll
            for (int j = 0; j < 4; ++j) {
                const float ax = __shfl_xor(a[j], 1);
                const float bx = __shfl_xor(bg[j], 1);
                const float si = half ? ax    : a[j];     // sigm(i)
                const float sf = half ? bx    : bg[j];    // sigm(f)
                const float tg = half ? a[j]  : ax;       // tanh(g)
                const float so = half ? bg[j] : bx;       // sigm(o)
                c[j] = fmaf(sf, c[j], si * tg);
                h[j] = so * tanhfast(c[j]);
            }
        }
        if (!half) {
            lastout[s][0] = h[0]; lastout[s][1] = h[1];
            lastout[s][2] = h[2]; lastout[s][3] = h[3];
        }
    }

    // ---------------- layer 1 backward: only ONE step needed ----------------
    // (output taken at last original position == first step of reversed seq;
    //  h0 = c0 = 0 so gates need only the input term)
    {
        const float* wihr = wih1b + half * 8 * 8;
        const float* bir  = bih1b + half * 8;
        const float* bhr  = bhh1b + half * 8;
        const float* base = l0out + (s * SEQLEN + SEQLEN - 1) * 8;
        float4 inA = *(const float4*)(base);
        float4 inB = *(const float4*)(base + 4);
        const float in[8] = {inA.x, inA.y, inA.z, inA.w, inB.x, inB.y, inB.z, inB.w};
        float g[8];
#pragma unroll
        for (int gi = 0; gi < 8; ++gi) {
            float acc = bir[gi] + bhr[gi];
#pragma unroll
            for (int k = 0; k < 8; ++k) acc = fmaf(wihr[gi * 8 + k], in[k], acc);
            g[gi] = acc;
        }
        float a[4], bg[4];
#pragma unroll
        for (int j = 0; j < 4; ++j) {
            a[j]  = half ? tanhfast(g[j]) : sigm(g[j]);
            bg[j] = sigm(g[4 + j]);
        }
#pragma unroll
        for (int j = 0; j < 4; ++j) {
            const float ax = __shfl_xor(a[j], 1);
            const float bx = __shfl_xor(bg[j], 1);
            const float si = half ? ax    : a[j];
            const float tg = half ? a[j]  : ax;
            const float so = half ? bg[j] : bx;
            const float cnew = si * tg;                  // c0 = 0
            const float hnew = so * tanhfast(cnew);
            if (!half) lastout[s][4 + j] = hnew;
        }
    }
    __syncthreads();

    // ---------------- FC1: hidden[b][m] = relu(feat[b] . w1[m]) -------------
    // feat[b][k] = lastout-flat[b*512 + k]   (k = c*8 + j)
    {
        const float* lastflat = &lastout[0][0];
        const int wave = tid >> 6, lane = tid & 63;
#pragma unroll
        for (int r = 0; r < 16; ++r) {
            const int o = wave * 16 + r;           // 0..63
            const int b = o >> 5, m = o & 31;
            float p = 0.f;
#pragma unroll
            for (int i = 0; i < 8; ++i) {
                const int k = lane + i * 64;
                p = fmaf(lastflat[b * 512 + k], w1[m * 512 + k], p);
            }
#pragma unroll
            for (int off = 32; off; off >>= 1) p += __shfl_down(p, off, 64);
            if (lane == 0) hidden[b * 32 + m] = fmaxf(p, 0.f);
        }
    }
    __syncthreads();

    // ---------------- FC2 + sigmoid -> per-channel scale ---------------------
    if (tid < 128) {
        const int b = tid >> 6, cc = tid & 63;
        float p = 0.f;
#pragma unroll
        for (int m = 0; m < 32; ++m)
            p = fmaf(hidden[b * 32 + m], w2[cc * 32 + m], p);
        scl[tid] = sigm(p);                       // tid == b*64 + cc
    }
}

// ---------------------------------------------------------------------------
// Kernel 3: out = x * scale[channel].
// REVERSE traversal: the mean pass streamed x forward, so the LLC (256 MB vs
// x = 302 MB) holds the TAIL of x.  Processing from the tail backwards turns
// most scale-pass reads into LLC hits.  Non-temporal stores keep `out` from
// allocating in (and evicting x from) the LLC.
// ---------------------------------------------------------------------------
__global__ __launch_bounds__(256) void scale_kernel(const float* __restrict__ x,
                                                    const float* __restrict__ scl,
                                                    float* __restrict__ out) {
    const int ch    = 127 - blockIdx.y;              // reverse channel order
    const int chunk = (NCHUNK - 1) - blockIdx.x;     // reverse chunk order
    const float sv = scl[ch];
    const size_t base = (size_t)ch * CHELEM + (size_t)chunk * 4096;
    const v4f* xp = (const v4f*)(x + base);
    v4f* op = (v4f*)(out + base);
    const int tid = threadIdx.x;
#pragma unroll
    for (int i = 0; i < 4; ++i) {
        v4f v = xp[tid + i * 256];
        v *= sv;
        __builtin_nontemporal_store(v, op + tid + i * 256);
    }
}

// ---------------------------------------------------------------------------
extern "C" void kernel_launch(void* const* d_in, const int* in_sizes, int n_in,
                              void* d_out, int out_size, void* d_ws, size_t ws_size,
                              hipStream_t stream) {
    const float* x     = (const float*)d_in[0];
    const float* wih0f = (const float*)d_in[1];
    const float* whh0f = (const float*)d_in[2];
    const float* bih0f = (const float*)d_in[3];
    const float* bhh0f = (const float*)d_in[4];
    const float* wih0b = (const float*)d_in[5];
    const float* whh0b = (const float*)d_in[6];
    const float* bih0b = (const float*)d_in[7];
    const float* bhh0b = (const float*)d_in[8];
    const float* wih1f = (const float*)d_in[9];
    const float* whh1f = (const float*)d_in[10];
    const float* bih1f = (const float*)d_in[11];
    const float* bhh1f = (const float*)d_in[12];
    const float* wih1b = (const float*)d_in[13];
    const float* whh1b = (const float*)d_in[14];
    const float* bih1b = (const float*)d_in[15];
    const float* bhh1b = (const float*)d_in[16];
    const float* w1    = (const float*)d_in[17];
    const float* w2    = (const float*)d_in[18];
    float* out = (float*)d_out;

    float* ws    = (float*)d_ws;
    float* means = ws;                        // 8192 floats
    float* l0out = ws + 8192;                 // 128*64*8 = 65536 floats
    float* scl   = ws + 8192 + 65536;         // 128 floats

    mean_kernel<<<dim3(8192), dim3(256), 0, stream>>>(x, means);
    lstm_fc_kernel<<<dim3(1), dim3(256), 0, stream>>>(
        means,
        wih0f, whh0f, bih0f, bhh0f, wih0b, whh0b, bih0b, bhh0b,
        wih1f, whh1f, bih1f, bhh1f, wih1b, whh1b, bih1b, bhh1b,
        w1, w2, l0out, scl);
    scale_kernel<<<dim3(NCHUNK, 128), dim3(256), 0, stream>>>(x, scl, out);
}